// Round 16
// baseline (55.849 us; speedup 1.0000x reference)
//
#include <hip/hip_runtime.h>
#include <cfloat>

#define KC    32768
#define NPTS  8192
#define TPB   256
#define PPT   8
#define PTS_PER_BLK (TPB * PPT)        // 2048
#define NPB   (NPTS / PTS_PER_BLK)     // 4
#define NC    256
#define CHUNK (KC / NC)                // 128

typedef float v2f __attribute__((ext_vector_type(2)));

// VOP3P with SCALAR-PAIR src0 (1 constant-bus read — legal). op_sel half H of
// the s-pair is broadcast to both result halves; b/c are 2-point VGPR pairs.
// IEEE per 32-bit half -> bit-identical to the verified scalar chain.
template<int H> __device__ __forceinline__ v2f pk_mul_sg(double a, v2f b) {
    v2f d;
    if constexpr (H == 0)
        asm("v_pk_mul_f32 %0, %1, %2 op_sel:[0,0] op_sel_hi:[0,1]" : "=v"(d) : "s"(a), "v"(b));
    else
        asm("v_pk_mul_f32 %0, %1, %2 op_sel:[1,0] op_sel_hi:[1,1]" : "=v"(d) : "s"(a), "v"(b));
    return d;
}
template<int H> __device__ __forceinline__ v2f pk_fma_sg(double a, v2f b, v2f c) {
    v2f d;
    if constexpr (H == 0)
        asm("v_pk_fma_f32 %0, %1, %2, %3 op_sel:[0,0,0] op_sel_hi:[0,1,1]" : "=v"(d) : "s"(a), "v"(b), "v"(c));
    else
        asm("v_pk_fma_f32 %0, %1, %2, %3 op_sel:[1,0,0] op_sel_hi:[1,1,1]" : "=v"(d) : "s"(a), "v"(b), "v"(c));
    return d;
}
template<int H> __device__ __forceinline__ v2f pk_add_sg(double a, v2f b) {
    v2f d;
    if constexpr (H == 0)
        asm("v_pk_add_f32 %0, %1, %2 op_sel:[0,0] op_sel_hi:[0,1]" : "=v"(d) : "s"(a), "v"(b));
    else
        asm("v_pk_add_f32 %0, %1, %2 op_sel:[1,0] op_sel_hi:[1,1]" : "=v"(d) : "s"(a), "v"(b));
    return d;
}
__device__ __forceinline__ v2f pk_add(v2f a, v2f b) {
    v2f d; asm("v_pk_add_f32 %0, %1, %2" : "=v"(d) : "v"(a), "v"(b)); return d;
}
__device__ __forceinline__ float min3f(float a, float b, float c) {
    float d; asm("v_min3_f32 %0, %1, %2, %3" : "=v"(d) : "v"(a), "v"(b), "v"(c)); return d;
}

// ---------------- K0: pack E into SoA (E0|E1|E2|E3|B) for scalar-pair loads
__global__ __launch_bounds__(256) void k_prep(const float* __restrict__ E,
                                              float* __restrict__ ec) {
#pragma clang fp contract(off)
    const int k = blockIdx.x * 256 + threadIdx.x;
    float4 e = ((const float4*)E)[k];
    ec[k]          = e.x;
    ec[KC + k]     = e.y;
    ec[2 * KC + k] = e.z;
    ec[3 * KC + k] = e.w;
    // bnorm: squares individually rounded, sequential adds (R1-verified)
    ec[4 * KC + k] = ((e.x * e.x + e.y * e.y) + e.z * e.z) + e.w * e.w;
}

// ---------------- K1: per-chunk MIN-DISTANCE ONLY. No LDS at all: code data
// streams through SGPRs (uniform addresses), points packed 2-per-pk-op.
// Chain uses x pre-scaled by -2: every partial is exactly -2x the reference
// partial (pow2 scaling commutes with rounding), so d = t + m2 == fl(t-fl(2m)).
__global__ __launch_bounds__(TPB) void k_dist(const float* __restrict__ x,
                                              const float* __restrict__ ec,
                                              float* __restrict__ dmn) {
#pragma clang fp contract(off)
    const double* E0 = (const double*)(ec);
    const double* E1 = (const double*)(ec + KC);
    const double* E2 = (const double*)(ec + 2 * KC);
    const double* E3 = (const double*)(ec + 3 * KC);
    const double* Bb = (const double*)(ec + 4 * KC);

    const int chunk = blockIdx.x;
    const int pblk  = blockIdx.y;
    const int tid   = threadIdx.x;
    const int kb2   = chunk * (CHUNK / 2);     // code-PAIR base (uniform)

    // 8 points as 4 pairs {ptA,ptB}: pre-scaled channels + unscaled a
    v2f Xm0[4], Xm1[4], Xm2[4], Xm3[4], Aab[4];
#pragma unroll
    for (int u = 0; u < 4; ++u) {
        float xs[2][4], aa[2];
#pragma unroll
        for (int h = 0; h < 2; ++h) {
            const int i = 2 * u + h;
            const int p = pblk * PTS_PER_BLK + i * TPB + tid;
            const int t = p >> 12, s = p & 4095;
            const int xb = t * 16384 + s;
            const float x0 = x[xb], x1 = x[xb + 4096], x2 = x[xb + 8192], x3 = x[xb + 12288];
            xs[h][0] = x0; xs[h][1] = x1; xs[h][2] = x2; xs[h][3] = x3;
            aa[h] = ((x0 * x0 + x1 * x1) + x2 * x2) + x3 * x3;
        }
        Xm0[u] = v2f{-2.0f * xs[0][0], -2.0f * xs[1][0]};
        Xm1[u] = v2f{-2.0f * xs[0][1], -2.0f * xs[1][1]};
        Xm2[u] = v2f{-2.0f * xs[0][2], -2.0f * xs[1][2]};
        Xm3[u] = v2f{-2.0f * xs[0][3], -2.0f * xs[1][3]};
        Aab[u] = v2f{aa[0], aa[1]};
    }

    float bdA[4], bdB[4];
#pragma unroll
    for (int u = 0; u < 4; ++u) { bdA[u] = FLT_MAX; bdB[u] = FLT_MAX; }

#pragma unroll 4
    for (int q = 0; q < CHUNK / 2; ++q) {      // 2 codes x 8 points per iter
        const double se0 = E0[kb2 + q];        // {e0(2q), e0(2q+1)} -> SGPR pair
        const double se1 = E1[kb2 + q];
        const double se2 = E2[kb2 + q];
        const double se3 = E3[kb2 + q];
        const double sb  = Bb[kb2 + q];
#pragma unroll
        for (int u = 0; u < 4; ++u) {
            // code 2q (half 0): m2 = -2m exactly; d = t + m2
            v2f m0 = pk_fma_sg<0>(se3, Xm3[u], pk_fma_sg<0>(se2, Xm2[u],
                      pk_fma_sg<0>(se1, Xm1[u], pk_mul_sg<0>(se0, Xm0[u]))));
            v2f t0 = pk_add_sg<0>(sb, Aab[u]);
            v2f d0 = pk_add(m0, t0);
            // code 2q+1 (half 1)
            v2f m1 = pk_fma_sg<1>(se3, Xm3[u], pk_fma_sg<1>(se2, Xm2[u],
                      pk_fma_sg<1>(se1, Xm1[u], pk_mul_sg<1>(se0, Xm0[u]))));
            v2f t1 = pk_add_sg<1>(sb, Aab[u]);
            v2f d1 = pk_add(m1, t1);
            bdA[u] = min3f(bdA[u], d0.x, d1.x);
            bdB[u] = min3f(bdB[u], d0.y, d1.y);
        }
    }
#pragma unroll
    for (int u = 0; u < 4; ++u) {
        const int pA = pblk * PTS_PER_BLK + (2 * u) * TPB + tid;
        const int pB = pblk * PTS_PER_BLK + (2 * u + 1) * TPB + tid;
        dmn[chunk * NPTS + pA] = bdA[u];
        dmn[chunk * NPTS + pB] = bdB[u];
    }
}

// ---------------- K2: merge chunk-mins, recover first-index k, gather, loss
// (verified absmax 0.0 in R12/R14 at NC=256; scalar rescan chain produces the
// same bitwise d values as the scaled pk chain above)
__global__ __launch_bounds__(256) void k_merge(const float* __restrict__ x,
                                               const float* __restrict__ E,
                                               const float* __restrict__ dmn,
                                               float* __restrict__ out,
                                               double* __restrict__ partials) {
#pragma clang fp contract(off)
    const int tid  = threadIdx.x;
    const int sub  = tid & 7;
    const int pidx = tid >> 3;                 // 0..31
    const int p    = blockIdx.x * 32 + pidx;   // 256 blocks x 32 points
    const int t    = p >> 12, s = p & 4095;
    const int xb   = t * 16384 + s;

    const float x0 = x[xb];
    const float x1 = x[xb + 4096];
    const float x2 = x[xb + 8192];
    const float x3 = x[xb + 12288];
    const float a  = ((x0 * x0 + x1 * x1) + x2 * x2) + x3 * x3;

    // min over chunks, tie -> smaller chunk id (lexicographic)
    float bd = FLT_MAX;
    int   bc = 0x7fffffff;
#pragma unroll 8
    for (int i = 0; i < NC / 8; ++i) {
        const int c = sub + 8 * i;             // ascending per sub
        float d = dmn[c * NPTS + p];
        if (d < bd) { bd = d; bc = c; }        // strict <: earliest c in sub set
    }
#pragma unroll
    for (int m = 1; m <= 4; m <<= 1) {
        float d2 = __shfl_xor(bd, m);
        int   c2 = __shfl_xor(bc, m);
        if (d2 < bd || (d2 == bd && c2 < bc)) { bd = d2; bc = c2; }
    }

    // rescan chunk bc: sub handles CHUNK/8 = 16 consecutive codes
    const int kb = bc * CHUNK;
    int jloc = 1 << 30;
    for (int jj = 0; jj < CHUNK / 8; ++jj) {
        const int j = sub * (CHUNK / 8) + jj;
        float4 e = ((const float4*)E)[kb + j];
        float bn = ((e.x * e.x + e.y * e.y) + e.z * e.z) + e.w * e.w;
        float m_ = __builtin_fmaf(x3, e.w, __builtin_fmaf(x2, e.z,
                    __builtin_fmaf(x1, e.y, x0 * e.x)));
        float t_ = a + bn;
        float d_ = __builtin_fmaf(-2.0f, m_, t_);
        if (d_ == bd) jloc = min(jloc, j);     // ascending j -> first match
    }
#pragma unroll
    for (int m = 1; m <= 4; m <<= 1) jloc = min(jloc, __shfl_xor(jloc, m));
    const int bk = kb + (jloc & (CHUNK - 1));  // clamp guards OOB if mismatch

    double ls = 0.0;
    if (sub < 4) {                             // one channel per sub-lane
        const int ch  = sub;
        const int idx = xb + ch * 4096;
        float xv   = x[idx];
        float ev   = E[bk * 4 + ch];
        float diff = ev - xv;                  // fl(z_q - x)
        float sq   = diff * diff;              // fl(diff^2)
        out[idx]   = xv + diff;                // z_q_st = fl(x + fl(z_q - x))
        ls = (double)sq;
        if (ch == 0) out[32769 + p] = (float)bk;  // codes as float
    }
#pragma unroll
    for (int m = 1; m < 64; m <<= 1) ls += __shfl_xor(ls, m);
    __shared__ double sred[4];
    if ((tid & 63) == 0) sred[tid >> 6] = ls;
    __syncthreads();
    if (tid == 0) partials[blockIdx.x] = sred[0] + sred[1] + sred[2] + sred[3];
}

// ---------------- K3: finalize qloss
__global__ void k_loss(const double* __restrict__ partials,
                       float* __restrict__ out) {
#pragma clang fp contract(off)
    if (threadIdx.x == 0 && blockIdx.x == 0) {
        double sum = 0.0;
        for (int i = 0; i < 256; ++i) sum += partials[i];
        float mu = (float)(sum * (1.0 / 32768.0));   // /32768 exact
        float q  = mu + 0.1f * mu;                   // mean1 + BETA*mean2
        out[32768] = q;
    }
}

extern "C" void kernel_launch(void* const* d_in, const int* in_sizes, int n_in,
                              void* d_out, int out_size, void* d_ws, size_t ws_size,
                              hipStream_t stream) {
    const float* x = (const float*)d_in[0];   // (1,2,4,64,64)
    const float* E = (const float*)d_in[1];   // (32768,4)
    float* out = (float*)d_out;               // 40961 floats

    char* ws = (char*)d_ws;
    double* partials = (double*)ws;                    // 2 KB
    float*  ec       = (float*)(ws + 2048);            // 5*KC*4 = 640 KB SoA
    float*  dmn      = (float*)(ws + 2048 + 5 * KC * 4); // 256*8192*4 = 8.4 MB

    k_prep<<<KC / 256, 256, 0, stream>>>(E, ec);
    dim3 g(NC, NPB);
    k_dist<<<g, TPB, 0, stream>>>(x, ec, dmn);
    k_merge<<<NPTS / 32, 256, 0, stream>>>(x, E, dmn, out, partials);
    k_loss<<<1, 64, 0, stream>>>(partials, out);
}